// Round 1
// 211.748 us; speedup vs baseline: 1.0212x; 1.0212x over previous
//
#include <hip/hip_runtime.h>

#define NF 50
#define NCARD 10000
#define FD 64
#define NPAIR 1225        // 50*49/2
#define NPAIR_PAD 1232    // 77*16
#define NTILE 77
#define NB 2              // batch elements per block (one per wave-pair)
#define FROWB 144         // bytes per field row in LDS (72 f16, non-pow2 -> 2-way max)
#define FBATB 7200        // bytes per batch section (50*144)

typedef _Float16 h16x8 __attribute__((ext_vector_type(8)));
typedef float f32x4 __attribute__((ext_vector_type(4)));
typedef float f32x2 __attribute__((ext_vector_type(2)));

// Single fused kernel: no workspace, no pre-pass.
// Tables that afm_pre used to build are recomputed per-block (cheap, hidden
// under the emb gather latency):
//   - poff pair table: ~5 int ops/thread
//   - W1^T MFMA fragments: 64 scattered 4B loads/lane from a 16 KB L1-resident array
__global__ __launch_bounds__(256, 4) void afm_fused(
    const int* __restrict__ x,
    const float* __restrict__ emb,
    const float* __restrict__ W1,
    const float* __restrict__ b1,
    const float* __restrict__ w2,
    const float* __restrict__ lin_w,
    const float* __restrict__ lin_b,
    float* __restrict__ out)
{
    __shared__ __align__(16) _Float16 fach[NB * 50 * 72]; // 14400 B
    __shared__ unsigned poff[NPAIR_PAD];                  // 4928 B
    __shared__ float cmb[4][3];

    const int b0   = blockIdx.x * NB;
    const int tid  = threadIdx.x;
    const int lane = tid & 63;
    const int wid  = tid >> 6;
    const int n16  = lane & 15;
    const int quad = lane >> 4;

    // ---- stage NB*50 factor rows as f16 ----
    for (int t = tid; t < NB * 50 * 8; t += 256) {
        int rowid = t >> 3, q = t & 7;
        int bb = (rowid >= 50) ? 1 : 0;
        int f = rowid - bb * 50;
        int gid = x[(b0 + bb) * NF + f] + f * NCARD;
        const float* src = emb + (size_t)gid * FD + q * 8;
        float4 v0 = *(const float4*)(src);
        float4 v1 = *(const float4*)(src + 4);
        h16x8 h;
        h[0] = (_Float16)v0.x; h[1] = (_Float16)v0.y;
        h[2] = (_Float16)v0.z; h[3] = (_Float16)v0.w;
        h[4] = (_Float16)v1.x; h[5] = (_Float16)v1.y;
        h[6] = (_Float16)v1.z; h[7] = (_Float16)v1.w;
        *(h16x8*)(fach + bb * 3600 + f * 72 + q * 8) = h;
    }

    // ---- pair-offset table, computed in-block (replaces afm_pre blocks 2-6) ----
    for (int p = tid; p < NPAIR_PAD; p += 256) {
        int i = 0, j = 0;
        if (p < NPAIR) {
            float disc = (float)((2 * NF - 1) * (2 * NF - 1) - 8 * p);
            i = (int)(((float)(2 * NF - 1) - sqrtf(disc)) * 0.5f);
            if (i < 0) i = 0;
            if (i > NF - 2) i = NF - 2;
            while (i + 1 <= NF - 2 && (i + 1) * (NF - 1) - ((i + 1) * i) / 2 <= p) ++i;
            while (i > 0 && i * (NF - 1) - (i * (i - 1)) / 2 > p) --i;
            j = p - (i * (NF - 1) - (i * (i - 1)) / 2) + i + 1;
        }
        poff[p] = (unsigned)(i * FROWB) | ((unsigned)(j * FROWB) << 16);
    }

    // ---- per-lane constants (register-resident) ----
    // W1^T fragments straight from global: A[m=a][k] layout for 16x16x32 f16,
    // a = mt*16+n16, k = ks*32 + quad*8 + jj. W1 is 16 KB -> L1/L2-hot.
    h16x8 afragW[8];
    #pragma unroll
    for (int s = 0; s < 8; ++s) {
        const int a  = (s >> 1) * 16 + n16;
        const int kb = (s & 1) * 32 + quad * 8;
        h16x8 v;
        #pragma unroll
        for (int jj = 0; jj < 8; ++jj)
            v[jj] = (_Float16)W1[(kb + jj) * 64 + a];
        afragW[s] = v;
    }
    h16x8 aones;                           // virtual ones-row tile -> inter_sum
    {
        _Float16 o = (n16 == 0) ? (_Float16)1.0f : (_Float16)0.0f;
        #pragma unroll
        for (int jj = 0; jj < 8; ++jj) aones[jj] = o;
    }
    f32x4 b1v[4];
    f32x2 w2lo[4], w2hi[4];                // C row = mt*16 + quad*4 + r
    #pragma unroll
    for (int mt = 0; mt < 4; ++mt) {
        const float4 bb = *(const float4*)(b1 + mt * 16 + quad * 4);
        const float4 ww = *(const float4*)(w2 + mt * 16 + quad * 4);
        b1v[mt]  = (f32x4){bb.x, bb.y, bb.z, bb.w};
        w2lo[mt] = (f32x2){ww.x, ww.y};
        w2hi[mt] = (f32x2){ww.z, ww.w};
    }
    __syncthreads();

    // ---- main loop: wave pair (2w, 2w+1) covers batch w; online softmax ----
    const int mybatch = wid >> 1;
    const char* fb = (const char*)fach + mybatch * FBATB;
    float m = -1e30f, se = 0.f, sei = 0.f;

    for (int t = (wid & 1); t < NTILE; t += 2) {
        const unsigned po = poff[t * 16 + n16];
        const char* pbi = fb + (po & 0xFFFFu) + quad * 16;
        const char* pbj = fb + (po >> 16) + quad * 16;

        h16x8 fi0 = *(const h16x8*)(pbi);
        h16x8 fj0 = *(const h16x8*)(pbj);
        h16x8 fi1 = *(const h16x8*)(pbi + 64);
        h16x8 fj1 = *(const h16x8*)(pbj + 64);
        h16x8 pr0 = fi0 * fj0;                     // 4x v_pk_mul_f16 each
        h16x8 pr1 = fi1 * fj1;

        f32x4 acc[4];
        #pragma unroll
        for (int mt = 0; mt < 4; ++mt) {
            acc[mt] = __builtin_amdgcn_mfma_f32_16x16x32_f16(afragW[mt * 2 + 0], pr0, b1v[mt], 0, 0, 0);
            acc[mt] = __builtin_amdgcn_mfma_f32_16x16x32_f16(afragW[mt * 2 + 1], pr1, acc[mt], 0, 0, 0);
        }
        f32x4 accS = __builtin_amdgcn_mfma_f32_16x16x32_f16(aones, pr0, (f32x4){0.f, 0.f, 0.f, 0.f}, 0, 0, 0);
        accS = __builtin_amdgcn_mfma_f32_16x16x32_f16(aones, pr1, accS, 0, 0, 0);

        // sum_a relu(h)*w2 via packed f32 fma (v_pk_fma_f32)
        f32x2 l2 = (f32x2){0.f, 0.f};
        #pragma unroll
        for (int mt = 0; mt < 4; ++mt) {
            f32x2 r0 = (f32x2){fmaxf(acc[mt][0], 0.f), fmaxf(acc[mt][1], 0.f)};
            f32x2 r1 = (f32x2){fmaxf(acc[mt][2], 0.f), fmaxf(acc[mt][3], 0.f)};
            l2 = r0 * w2lo[mt] + l2;
            l2 = r1 * w2hi[mt] + l2;
        }
        float lacc = l2[0] + l2[1];
        lacc += __shfl_xor(lacc, 16, 64);          // reduce over att rows
        lacc += __shfl_xor(lacc, 32, 64);
        float is = __shfl(accS[0], n16, 64);       // inter_sum lives in quad-0 row 0

        if (t * 16 + n16 >= NPAIR) lacc = -1e30f;  // padded pairs (tile 76 only)

        // defer-max online softmax: when no lane's max grows, skip rescale
        // (exact: slow path with nm==m has sc==1)
        if (__all(lacc <= m)) {
            float e = __expf(lacc - m);
            se  += e;
            sei += e * is;
        } else {
            float nm = fmaxf(m, lacc);
            float sc = __expf(m - nm);
            float e  = __expf(lacc - nm);
            se  = se * sc + e;
            sei = sei * sc + e * is;
            m = nm;
        }
    }

    // merge per-lane online states across the 16 pair-residues (quads replicated)
    #pragma unroll
    for (int d = 1; d <= 8; d <<= 1) {
        float m2   = __shfl_xor(m, d, 64);
        float se2  = __shfl_xor(se, d, 64);
        float sei2 = __shfl_xor(sei, d, 64);
        float nm = fmaxf(m, m2);
        float a = __expf(m - nm), bsc = __expf(m2 - nm);
        se  = se * a + se2 * bsc;
        sei = sei * a + sei2 * bsc;
        m = nm;
    }

    // linear term: even wave of each pair gathers lin_w
    float lin = 0.f;
    if ((wid & 1) == 0) {
        if (lane < NF) {
            int gid = x[(b0 + mybatch) * NF + lane] + lane * NCARD;
            lin = lin_w[gid];
        }
        #pragma unroll
        for (int d = 1; d <= 32; d <<= 1) lin += __shfl_xor(lin, d, 64);
    }

    // cross-wave combine (one barrier) + output
    if (lane == 0) { cmb[wid][0] = m; cmb[wid][1] = se; cmb[wid][2] = sei; }
    __syncthreads();
    if ((wid & 1) == 0 && lane == 0) {
        float m2 = cmb[wid + 1][0], se2 = cmb[wid + 1][1], sei2 = cmb[wid + 1][2];
        float nm = fmaxf(m, m2);
        float a = __expf(m - nm), bsc = __expf(m2 - nm);
        float tse  = se * a + se2 * bsc;
        float tsei = sei * a + sei2 * bsc;
        out[b0 + mybatch] = lin + lin_b[0] + tsei / tse;
    }
}

extern "C" void kernel_launch(void* const* d_in, const int* in_sizes, int n_in,
                              void* d_out, int out_size, void* d_ws, size_t ws_size,
                              hipStream_t stream) {
    const int*   x     = (const int*)d_in[0];
    const float* emb   = (const float*)d_in[1];
    const float* W1    = (const float*)d_in[2];
    const float* b1    = (const float*)d_in[3];
    const float* w2    = (const float*)d_in[4];
    // d_in[5] = b2 : constant shift on logits, cancels in softmax
    const float* lin_w = (const float*)d_in[6];
    const float* lin_b = (const float*)d_in[7];
    float* out = (float*)d_out;

    const int batch = out_size; // 2048
    // NOTE: d_ws intentionally unused — single fused kernel, no workspace.
    afm_fused<<<batch / NB, 256, 0, stream>>>(x, emb, W1, b1, w2, lin_w, lin_b, out);
}